// Round 9
// baseline (365.295 us; speedup 1.0000x reference)
//
#include <hip/hip_runtime.h>
#include <hip/hip_bf16.h>

// ---------------------------------------------------------------------------
// Types + portability shims
// ---------------------------------------------------------------------------
typedef __attribute__((ext_vector_type(8))) short  s16x8;
typedef __attribute__((ext_vector_type(8))) __bf16 b16x8;
typedef __attribute__((ext_vector_type(4))) float  f32x4;

template <class...> struct make_void_ { typedef void type; };
template <class... Ts> using void_t_ = typename make_void_<Ts...>::type;

// MFMA wrapper: compiles whether the builtin takes short8 or bf16x8 operands.
template <typename V, typename = void>
struct MfmaBF16 {
  static __device__ __forceinline__ f32x4 run(V a, V b, f32x4 c) {
    return __builtin_amdgcn_mfma_f32_16x16x32_bf16(
        __builtin_bit_cast(b16x8, a), __builtin_bit_cast(b16x8, b), c, 0, 0, 0);
  }
};
template <typename V>
struct MfmaBF16<V, void_t_<decltype(__builtin_amdgcn_mfma_f32_16x16x32_bf16(
                      V{}, V{}, f32x4{}, 0, 0, 0))>> {
  static __device__ __forceinline__ f32x4 run(V a, V b, f32x4 c) {
    return __builtin_amdgcn_mfma_f32_16x16x32_bf16(a, b, c, 0, 0, 0);
  }
};
__device__ __forceinline__ f32x4 mfma16(s16x8 a, s16x8 b, f32x4 c) {
  return MfmaBF16<s16x8>::run(a, b, c);
}

__device__ __forceinline__ unsigned short f2bf(float f) {  // RNE f32->bf16
  union { float f; unsigned u; } v; v.f = f;
  return (unsigned short)((v.u + 0x7FFFu + ((v.u >> 16) & 1u)) >> 16);
}
__device__ __forceinline__ float bf2f(unsigned short s) {
  union { unsigned u; float f; } v; v.u = ((unsigned)s) << 16;
  return v.f;
}

// async global->LDS, 16B per lane, LDS dest = wave-uniform base + lane*16
__device__ __forceinline__ void gload16(const void* g, void* l) {
  __builtin_amdgcn_global_load_lds(
      (const __attribute__((address_space(1))) unsigned int*)g,
      (__attribute__((address_space(3))) unsigned int*)l, 16, 0, 0);
}

// ---------------------------------------------------------------------------
// fp32 -> bf16 elementwise. grid*256*4 must equal element count.
// ---------------------------------------------------------------------------
__global__ __launch_bounds__(256) void cvt_f32_bf16(const float* __restrict__ X,
                                                    unsigned short* __restrict__ Y) {
  int i = (blockIdx.x * 256 + threadIdx.x) * 4;
  float4 v = *(const float4*)&X[i];
  ushort4 o;
  o.x = f2bf(v.x); o.y = f2bf(v.y); o.z = f2bf(v.z); o.w = f2bf(v.w);
  *(ushort4*)&Y[i] = o;
}

// Four W [1024][1024] f32 row-major -> Wt [n][k] bf16 (transposed), z selects.
__global__ __launch_bounds__(256) void transpose_w4(
    const float* __restrict__ W0, const float* __restrict__ W1,
    const float* __restrict__ W2, const float* __restrict__ W3,
    unsigned short* __restrict__ T0, unsigned short* __restrict__ T1,
    unsigned short* __restrict__ T2, unsigned short* __restrict__ T3) {
  __shared__ __align__(16) float T[64][68];
  const int z = blockIdx.z;
  const float* W = (z == 0) ? W0 : (z == 1) ? W1 : (z == 2) ? W2 : W3;
  unsigned short* Wt = (z == 0) ? T0 : (z == 1) ? T1 : (z == 2) ? T2 : T3;
  const int tid = threadIdx.x;
  const int k0 = blockIdx.y * 64, n0 = blockIdx.x * 64;
  #pragma unroll
  for (int i = 0; i < 4; ++i) {
    int idx = i * 256 + tid;
    int r = idx >> 4, c4 = idx & 15;
    *(f32x4*)&T[r][c4 * 4] = *(const f32x4*)&W[(long)(k0 + r) * 1024 + n0 + c4 * 4];
  }
  __syncthreads();
  #pragma unroll
  for (int i = 0; i < 4; ++i) {
    int idx = i * 256 + tid;
    int rn = idx >> 4, c4 = idx & 15;
    ushort4 o;
    o.x = f2bf(T[c4 * 4 + 0][rn]);
    o.y = f2bf(T[c4 * 4 + 1][rn]);
    o.z = f2bf(T[c4 * 4 + 2][rn]);
    o.w = f2bf(T[c4 * 4 + 3][rn]);
    *(ushort4*)&Wt[(long)(n0 + rn) * 1024 + k0 + c4 * 4] = o;
  }
}

// ---------------------------------------------------------------------------
// GEMM: Y = A[M x 1024] @ Bt^T + bias, A/Bt bf16, Bt stored [n][k].
// Tile 128(M) x 64(N), BK=64, 256 thr (4 waves, 2x2), mfma 16x16x32 bf16.
// LDS staged via global_load_lds; source pre-swizzled chunk^=(row&7), reads
// apply the same XOR (involution, rule #21). All MFMA-feeding ds_read_b128
// land 2-way per bank (free, m136).
// mode 0: f32 row-major [M][1024]; mode 1: bf16 [b,h,l,dk]; mode 2: bf16 [b,h,dk,l]
// ---------------------------------------------------------------------------
__global__ __launch_bounds__(256) void gemm_bf16(
    const unsigned short* __restrict__ A,
    const unsigned short* __restrict__ Bt,
    const float* __restrict__ bias,
    void* __restrict__ Y, int mode) {
  __shared__ __align__(16) unsigned short As[128][64];  // 16 KB
  __shared__ __align__(16) unsigned short Bs[64][64];   // 8 KB
  const int tid = threadIdx.x;
  const int lane = tid & 63, w = tid >> 6;
  const int g = lane >> 4, ln = lane & 15;
  const int wr = w >> 1, wc = w & 1;
  const int m0 = blockIdx.y * 128, n0 = blockIdx.x * 64;

  f32x4 acc[4][2] = {};

  for (int k0 = 0; k0 < 1024; k0 += 64) {
    #pragma unroll
    for (int i = 0; i < 4; ++i) {  // A tile: 16 wave-calls (4/wave)
      int slot = (w * 4 + i) * 64 + lane;
      int row = slot >> 3, c = slot & 7;
      gload16(&A[(long)(m0 + row) * 1024 + k0 + ((c ^ (row & 7)) << 3)],
              ((unsigned short*)As) + (w * 4 + i) * 512);
    }
    #pragma unroll
    for (int i = 0; i < 2; ++i) {  // B tile: 8 wave-calls (2/wave)
      int slot = (w * 2 + i) * 64 + lane;
      int row = slot >> 3, c = slot & 7;
      gload16(&Bt[(long)(n0 + row) * 1024 + k0 + ((c ^ (row & 7)) << 3)],
              ((unsigned short*)Bs) + (w * 2 + i) * 512);
    }
    __syncthreads();
    #pragma unroll
    for (int ks = 0; ks < 2; ++ks) {
      s16x8 af[4], bfr[2];
      #pragma unroll
      for (int pi = 0; pi < 4; ++pi) {
        int r = wr * 64 + pi * 16 + ln;
        af[pi] = *(const s16x8*)&As[r][((4 * ks + g) ^ (r & 7)) << 3];
      }
      #pragma unroll
      for (int ni = 0; ni < 2; ++ni) {
        int r = wc * 32 + ni * 16 + ln;
        bfr[ni] = *(const s16x8*)&Bs[r][((4 * ks + g) ^ (r & 7)) << 3];
      }
      #pragma unroll
      for (int pi = 0; pi < 4; ++pi)
        #pragma unroll
        for (int ni = 0; ni < 2; ++ni)
          acc[pi][ni] = mfma16(af[pi], bfr[ni], acc[pi][ni]);
    }
    __syncthreads();
  }

  float bb[2];
  bb[0] = bias[n0 + wc * 32 + ln];
  bb[1] = bias[n0 + wc * 32 + 16 + ln];
  #pragma unroll
  for (int pi = 0; pi < 4; ++pi) {
    #pragma unroll
    for (int ni = 0; ni < 2; ++ni) {
      int n = n0 + wc * 32 + ni * 16 + ln;
      int mb = m0 + wr * 64 + pi * 16 + 4 * g;  // rows mb..mb+3 (D: row=4g+r, col=ln)
      if (mode == 0) {
        float* O = (float*)Y;
        #pragma unroll
        for (int r = 0; r < 4; ++r)
          O[(long)(mb + r) * 1024 + n] = acc[pi][ni][r] + bb[ni];
      } else if (mode == 1) {  // [b,h,l,dk]
        unsigned short* O = (unsigned short*)Y;
        int hh = n >> 6, dk = n & 63;
        #pragma unroll
        for (int r = 0; r < 4; ++r) {
          int m = mb + r, b = m >> 11, l = m & 2047;
          O[(((long)(b * 16 + hh) * 2048 + l) << 6) + dk] = f2bf(acc[pi][ni][r] + bb[ni]);
        }
      } else {  // [b,h,dk,l], 4 consecutive l -> one 8B store
        unsigned short* O = (unsigned short*)Y;
        int hh = n >> 6, dk = n & 63;
        int b = mb >> 11, l = mb & 2047;
        ushort4 o;
        o.x = f2bf(acc[pi][ni][0] + bb[ni]);
        o.y = f2bf(acc[pi][ni][1] + bb[ni]);
        o.z = f2bf(acc[pi][ni][2] + bb[ni]);
        o.w = f2bf(acc[pi][ni][3] + bb[ni]);
        *(ushort4*)&O[((long)(b * 16 + hh) * 64 + dk) * 2048 + l] = o;
      }
    }
  }
}

// ---------------------------------------------------------------------------
// Fused flash attention, one (b, h, 64-query tile) per block, 256 thr / 4 waves.
// K,Q: [b,h,l,dk] bf16; V: [b,h,dk,l] bf16 (transposed).
// Wave w owns query rows 16w..16w+15. S' = Q.K^T (MFMA), softmax over keys in
// fp32 LDS (4 threads/row), alpha->bf16 swizzled tile, PV MFMA, online rescale.
// Denominator lst accumulates the bf16-ROUNDED alphas so the final divide
// normalizes by exactly the weights the PV MFMA applied.
// s_setprio(1) wraps the MFMA clusters (T5): cross-block wave arbitration,
// +4-7% on attention-like structures (m191), null on lockstep GEMM (m190).
// ---------------------------------------------------------------------------
__global__ __launch_bounds__(256) void attn_mfma(
    const unsigned short* __restrict__ Kp,
    const unsigned short* __restrict__ Vtp,
    const unsigned short* __restrict__ Qp,
    const float* __restrict__ mask_attn,  // [2048,2048], indexed [p][l]
    const float* __restrict__ mask_pad,   // [2,2048]
    unsigned short* __restrict__ Otb) {   // [4096][1024] bf16 row-major
  __shared__ __align__(16) unsigned short Qs[64][64], Ks[64][64], Vs[64][64], Pb[64][64];
  __shared__ __align__(16) float Sf[64][68];
  __shared__ __align__(16) float mst[64], lst[64], corr[64], mpd[64];
  __shared__ __align__(16) float pmax[4][64], psum[4][64];

  const int tid = threadIdx.x;
  const int lane = tid & 63, w = tid >> 6;
  const int g = lane >> 4, ln = lane & 15;
  const int p0 = blockIdx.x * 64;
  const int h = blockIdx.y, b = blockIdx.z;

  const unsigned short* Kh = Kp + (long)(b * 16 + h) * 2048 * 64;
  const unsigned short* Vh = Vtp + (long)(b * 16 + h) * 64 * 2048;
  const unsigned short* Qh = Qp + (long)(b * 16 + h) * 2048 * 64;

  #pragma unroll
  for (int i = 0; i < 2; ++i) {  // stage Q tile (8 KB)
    int slot = (w * 2 + i) * 64 + lane;
    int row = slot >> 3, c = slot & 7;
    gload16(&Qh[(long)(p0 + row) * 64 + ((c ^ (row & 7)) << 3)],
            ((unsigned short*)Qs) + (w * 2 + i) * 512);
  }
  if (tid < 64) { mst[tid] = -3e38f; lst[tid] = 0.f; }

  f32x4 acc[4] = {};  // O rows 16w+4g+r, cols 16di+ln

  for (int l0 = 0; l0 < 2048; l0 += 64) {
    #pragma unroll
    for (int i = 0; i < 2; ++i) {  // stage K + V^T tiles
      int slot = (w * 2 + i) * 64 + lane;
      int row = slot >> 3, c = slot & 7;
      gload16(&Kh[(long)(l0 + row) * 64 + ((c ^ (row & 7)) << 3)],
              ((unsigned short*)Ks) + (w * 2 + i) * 512);
      gload16(&Vh[(long)row * 2048 + l0 + ((c ^ (row & 7)) << 3)],
              ((unsigned short*)Vs) + (w * 2 + i) * 512);
    }
    if (tid < 64) mpd[tid] = mask_pad[b * 2048 + l0 + tid];
    __syncthreads();  // (1) staging drained

    // ---- S' = Q.K^T, rows = queries 16w..16w+15, cols = keys l0..l0+63
    f32x4 sacc[4] = {};
    __builtin_amdgcn_s_setprio(1);
    #pragma unroll
    for (int ks = 0; ks < 2; ++ks) {
      int rq = 16 * w + ln;
      s16x8 aq = *(const s16x8*)&Qs[rq][((4 * ks + g) ^ (rq & 7)) << 3];
      #pragma unroll
      for (int li = 0; li < 4; ++li) {
        int rk = 16 * li + ln;
        s16x8 bk = *(const s16x8*)&Ks[rk][((4 * ks + g) ^ (rk & 7)) << 3];
        sacc[li] = mfma16(aq, bk, sacc[li]);
      }
    }
    __builtin_amdgcn_s_setprio(0);
    #pragma unroll
    for (int li = 0; li < 4; ++li)
      #pragma unroll
      for (int r = 0; r < 4; ++r)
        Sf[16 * w + 4 * g + r][16 * li + ln] = sacc[li][r] * 0.125f;
    __syncthreads();  // (2)

    // ---- masks + per-thread max (4 threads per query row)
    {
      int p = tid >> 2, q = tid & 3;
      f32x4* srow = (f32x4*)&Sf[p][q * 16];
      const f32x4* marow =
          (const f32x4*)(mask_attn + (long)(p0 + p) * 2048 + l0 + q * 16);
      const f32x4* mprow = (const f32x4*)&mpd[q * 16];
      float mx = -3e38f;
      #pragma unroll
      for (int i = 0; i < 4; ++i) {
        f32x4 s = srow[i] + marow[i] + mprow[i];
        srow[i] = s;
        mx = fmaxf(fmaxf(fmaxf(s[0], s[1]), fmaxf(s[2], s[3])), mx);
      }
      pmax[q][p] = mx;
    }
    __syncthreads();  // (3)
    if (tid < 64) {
      int p = tid;
      float mn = fmaxf(fmaxf(pmax[0][p], pmax[1][p]), fmaxf(pmax[2][p], pmax[3][p]));
      mn = fmaxf(mn, mst[p]);
      float c = __expf(mst[p] - mn);
      corr[p] = c; lst[p] *= c; mst[p] = mn;
    }
    __syncthreads();  // (4)

    // ---- alpha = exp(S-m) -> bf16 Pb (swizzled); sums use the ROUNDED alphas
    {
      int p = tid >> 2, q = tid & 3;
      const f32x4* srow = (const f32x4*)&Sf[p][q * 16];
      float m = mst[p], sum = 0.f;
      #pragma unroll
      for (int j = 0; j < 2; ++j) {
        unsigned short tmp[8];
        #pragma unroll
        for (int e = 0; e < 8; ++e) {
          float a = __expf(srow[2 * j + (e >> 2)][e & 3] - m);
          unsigned short us = f2bf(a);
          sum += bf2f(us);
          tmp[e] = us;
        }
        *(s16x8*)&Pb[p][((2 * q + j) ^ (p & 7)) << 3] = *(const s16x8*)tmp;
      }
      psum[q][p] = sum;
    }
    __syncthreads();  // (5)
    if (tid < 64) lst[tid] += psum[0][tid] + psum[1][tid] + psum[2][tid] + psum[3][tid];

    // ---- PV: rescale then acc += P.V  (B-frag rows of V^T = d)
    f32x4 cr = *(const f32x4*)&corr[16 * w + 4 * g];
    #pragma unroll
    for (int di = 0; di < 4; ++di) acc[di] *= cr;
    __builtin_amdgcn_s_setprio(1);
    #pragma unroll
    for (int ks = 0; ks < 2; ++ks) {
      int rp = 16 * w + ln;
      s16x8 ap = *(const s16x8*)&Pb[rp][((4 * ks + g) ^ (rp & 7)) << 3];
      #pragma unroll
      for (int di = 0; di < 4; ++di) {
        int rv = 16 * di + ln;
        s16x8 bv = *(const s16x8*)&Vs[rv][((4 * ks + g) ^ (rv & 7)) << 3];
        acc[di] = mfma16(ap, bv, acc[di]);
      }
    }
    __builtin_amdgcn_s_setprio(0);
    __syncthreads();  // (6) protect Ks/Vs/Pb for next tile
  }

  f32x4 lv = *(const f32x4*)&lst[16 * w + 4 * g];
  #pragma unroll
  for (int di = 0; di < 4; ++di) {
    int d = 16 * di + ln;
    #pragma unroll
    for (int r = 0; r < 4; ++r) {
      int p = p0 + 16 * w + 4 * g + r;
      Otb[((long)(b * 2048 + p) << 10) + h * 64 + d] = f2bf(acc[di][r] / lv[r]);
    }
  }
}

// ---------------------------------------------------------------------------
extern "C" void kernel_launch(void* const* d_in, const int* in_sizes, int n_in,
                              void* d_out, int out_size, void* d_ws, size_t ws_size,
                              hipStream_t stream) {
  const float* K_in      = (const float*)d_in[0];
  const float* V_in      = (const float*)d_in[1];
  const float* Q_in      = (const float*)d_in[2];
  const float* mask_attn = (const float*)d_in[3];
  const float* mask_pad  = (const float*)d_in[4];
  const float* Wk        = (const float*)d_in[5];
  const float* bk        = (const float*)d_in[6];
  const float* Wv        = (const float*)d_in[7];
  const float* bv        = (const float*)d_in[8];
  const float* Wq        = (const float*)d_in[9];
  const float* bq        = (const float*)d_in[10];
  const float* Wo        = (const float*)d_in[11];
  const float* bo        = (const float*)d_in[12];

  // workspace (bf16 elements), 40 MB total:
  //   X   : 4M shorts (8 MB) — staged input conversion, later reused as Otb
  //   Kp/Qp/Vtp : 4M each (24 MB)
  //   Wkt/Wvt/Wqt/Wot : 1M each (8 MB)
  const long MX = 4096L * 1024;
  const long MW = 1024L * 1024;
  unsigned short* ws  = (unsigned short*)d_ws;
  unsigned short* X   = ws;            // also Otb
  unsigned short* Kp  = X + MX;
  unsigned short* Qp  = Kp + MX;
  unsigned short* Vtp = Qp + MX;
  unsigned short* Wkt = Vtp + MX;
  unsigned short* Wvt = Wkt + MW;
  unsigned short* Wqt = Wvt + MW;
  unsigned short* Wot = Wqt + MW;

  dim3 blk(256);
  dim3 gg(16, 32);  // GEMM grid: 1024/64 n-blocks x 4096/128 m-blocks

  // 0) weights -> bf16 transposed [n][k] (one fused launch)
  hipLaunchKernelGGL(transpose_w4, dim3(16, 16, 4), blk, 0, stream,
                     Wk, Wv, Wq, Wo, Wkt, Wvt, Wqt, Wot);

  // 1) projections (cvt input -> X, then MFMA GEMM), X reused sequentially
  hipLaunchKernelGGL(cvt_f32_bf16, dim3(4096), blk, 0, stream, K_in, X);
  hipLaunchKernelGGL(gemm_bf16, gg, blk, 0, stream, X, Wkt, bk, (void*)Kp, 1);
  hipLaunchKernelGGL(cvt_f32_bf16, dim3(4096), blk, 0, stream, Q_in, X);
  hipLaunchKernelGGL(gemm_bf16, gg, blk, 0, stream, X, Wqt, bq, (void*)Qp, 1);
  hipLaunchKernelGGL(cvt_f32_bf16, dim3(4096), blk, 0, stream, V_in, X);
  hipLaunchKernelGGL(gemm_bf16, gg, blk, 0, stream, X, Wvt, bv, (void*)Vtp, 2);

  // 2) fused attention -> Otb (aliases X; previous contents dead)
  hipLaunchKernelGGL(attn_mfma, dim3(32, 16, 2), blk, 0, stream,
                     Kp, Vtp, Qp, mask_attn, mask_pad, X);

  // 3) output projection -> fp32 d_out
  hipLaunchKernelGGL(gemm_bf16, gg, blk, 0, stream, X, Wot, bo, d_out, 0);
}